// Round 4
// baseline (65.055 us; speedup 1.0000x reference)
//
#include <hip/hip_runtime.h>
#include <hip/hip_bf16.h>

#define BATCH 8
#define SEQ   2048
#define DIM   512
#define HD    64
#define NEGV  (-1e30f)
#define ROWS  (BATCH * SEQ)   // 16384

typedef float f32x4  __attribute__((ext_vector_type(4)));
typedef short bf16x8 __attribute__((ext_vector_type(8)));
typedef short bf16x4 __attribute__((ext_vector_type(4)));

__device__ __forceinline__ short f2bf(float f) {
  unsigned u = __builtin_bit_cast(unsigned, f);
  u += 0x7fffu + ((u >> 16) & 1u);
  return (short)(u >> 16);
}

// ---------------- Kernel 0: W transpose+convert -> Wt bf16 [192][512] -------
__global__ __launch_bounds__(256) void prep_w(
    const float* __restrict__ Wq, const float* __restrict__ Wk,
    const float* __restrict__ Wv, short* __restrict__ Wt)
{
  __shared__ float lds[64][65];
  const int mat = blockIdx.x % 3;
  const int kb  = blockIdx.x / 3;
  const float* W = mat == 0 ? Wq : (mat == 1 ? Wk : Wv);
  const int tid = threadIdx.x;

  #pragma unroll
  for (int i = 0; i < 4; ++i) {
    const int kr = i * 16 + (tid >> 4);
    const int col = (tid & 15) * 4;
    *(float4*)&lds[kr][col] = *(const float4*)&W[(kb * 64 + kr) * HD + col];
  }
  __syncthreads();
  #pragma unroll
  for (int i = 0; i < 2; ++i) {
    const int c = tid + i * 256;
    const int n = c >> 3, seg = c & 7;
    bf16x8 o;
    #pragma unroll
    for (int j = 0; j < 8; ++j) o[j] = f2bf(lds[seg * 8 + j][n]);
    *(bf16x8*)&Wt[(mat * 64 + n) * DIM + kb * 64 + seg * 8] = o;
  }
}

// ---------------- Kernel 1: QKV projection via MFMA (32-row tiles) ----------
__global__ __launch_bounds__(256) void qkv_gemm(
    const float* __restrict__ x, const short* __restrict__ Wt,
    const float* __restrict__ bq, const float* __restrict__ bk,
    const float* __restrict__ bv,
    short* __restrict__ Qb, short* __restrict__ Kb, short* __restrict__ Vt)
{
  __shared__ short xs[32 * 40];
  __shared__ short ws[192 * 40];

  const int tid  = threadIdx.x;
  const int lane = tid & 63;
  const int w    = tid >> 6;
  const int lc   = lane & 15;
  const int lg   = lane >> 4;
  const long r0  = (long)blockIdx.x * 32;

  f32x4 acc[2][3];
  #pragma unroll
  for (int m = 0; m < 2; ++m)
    #pragma unroll
    for (int n = 0; n < 3; ++n)
      #pragma unroll
      for (int i = 0; i < 4; ++i) acc[m][n][i] = 0.f;

  float4 xv;
  bf16x8 wv[3];
  const int xrow = tid >> 3, xseg = tid & 7;

  auto load_tile = [&](int k0) {
    xv = *(const float4*)&x[(r0 + xrow) * DIM + k0 + xseg * 4];
    #pragma unroll
    for (int i = 0; i < 3; ++i) {
      const int c = tid + i * 256, row = c >> 2, seg = c & 3;
      wv[i] = *(const bf16x8*)&Wt[row * DIM + k0 + seg * 8];
    }
  };
  auto write_tile = [&]() {
    bf16x4 t;
    t[0] = f2bf(xv.x); t[1] = f2bf(xv.y);
    t[2] = f2bf(xv.z); t[3] = f2bf(xv.w);
    *(bf16x4*)&xs[xrow * 40 + xseg * 4] = t;
    #pragma unroll
    for (int i = 0; i < 3; ++i) {
      const int c = tid + i * 256, row = c >> 2, seg = c & 3;
      *(bf16x8*)&ws[row * 40 + seg * 8] = wv[i];
    }
  };

  load_tile(0);
  write_tile();
  __syncthreads();

  for (int kt = 0; kt < 16; ++kt) {
    if (kt < 15) load_tile((kt + 1) * 32);

    bf16x8 a[2], b[3];
    #pragma unroll
    for (int m = 0; m < 2; ++m)
      a[m] = *(const bf16x8*)&xs[(m * 16 + lc) * 40 + lg * 8];
    #pragma unroll
    for (int n = 0; n < 3; ++n)
      b[n] = *(const bf16x8*)&ws[(w * 48 + n * 16 + lc) * 40 + lg * 8];
    __builtin_amdgcn_s_setprio(1);
    #pragma unroll
    for (int m = 0; m < 2; ++m)
      #pragma unroll
      for (int n = 0; n < 3; ++n)
        acc[m][n] = __builtin_amdgcn_mfma_f32_16x16x32_bf16(a[m], b[n], acc[m][n], 0, 0, 0);
    __builtin_amdgcn_s_setprio(0);

    __syncthreads();
    if (kt < 15) {
      write_tile();
      __syncthreads();
    }
  }

  #pragma unroll
  for (int n = 0; n < 3; ++n) {
    const int col = w * 48 + n * 16 + lc;
    const int mat = col >> 6;
    const int h   = col & 63;
    const float bias = (mat == 0 ? bq : (mat == 1 ? bk : bv))[h];
    #pragma unroll
    for (int m = 0; m < 2; ++m)
      #pragma unroll
      for (int r = 0; r < 4; ++r) {
        const long row = r0 + m * 16 + lg * 4 + r;
        const short o = f2bf(acc[m][n][r] + bias);
        if (mat == 0)      Qb[row * HD + h] = o;
        else if (mat == 1) Kb[row * HD + h] = o;
        else {
          const int bb = (int)(row >> 11), t = (int)(row & 2047);
          Vt[((long)bb * HD + h) * SEQ + t] = o;
        }
      }
  }
}

// ---------------- Kernel 2: barrier-free flash attention, 4-way split-K -----
// SPLIT: grid 1024. quarter = bid>>8; qt mirrored on odd quarters so the 4
// blocks that co-reside on a CU (bid, bid+256, ...) have constant total cost.
// No __syncthreads anywhere: waves read K/V MFMA fragments straight from
// global (L2-resident: per-batch K+V = 512 KB bf16).
template<bool SPLIT>
__global__ __launch_bounds__(256) void attn_kernel(
    const short* __restrict__ Qb, const short* __restrict__ Kb,
    const short* __restrict__ Vt, const unsigned char* __restrict__ pmask,
    float* __restrict__ out, float* __restrict__ Opart, float* __restrict__ ml)
{
  __shared__ short p_lds[4][16 * 72];

  const int bid = blockIdx.x;
  int b, qt, quarter;
  if (SPLIT) {
    quarter = bid >> 8;
    const int t = bid & 255;
    b = t >> 5;
    const int v = t & 31;
    qt = (quarter & 1) ? 31 - v : v;
  } else {
    b = bid >> 5; qt = bid & 31; quarter = 0;
  }

  const int nkt      = qt + 1;
  const int kt_begin = SPLIT ? (nkt * quarter) >> 2 : 0;
  const int kt_end   = SPLIT ? (nkt * (quarter + 1)) >> 2 : nkt;
  const int q0       = qt * 64;
  const int tid      = threadIdx.x;

  if (SPLIT && kt_begin >= kt_end) {
    #pragma unroll
    for (int i = 0; i < 4; ++i) {
      const int idx = tid + i * 256;            // 64 rows x 16 f32x4
      const int rr = idx >> 4;
      const long row = (long)b * SEQ + q0 + rr;
      f32x4 z; z[0] = 0.f; z[1] = 0.f; z[2] = 0.f; z[3] = 0.f;
      *(f32x4*)&Opart[((long)quarter * ROWS + row) * HD + (idx & 15) * 4] = z;
    }
    if (tid < 64) {
      const long row = (long)b * SEQ + q0 + tid;
      ml[((long)quarter * ROWS + row) * 2 + 0] = NEGV;
      ml[((long)quarter * ROWS + row) * 2 + 1] = 0.f;
    }
    return;
  }

  const int w    = tid >> 6;
  const int lane = tid & 63;
  const int lc   = lane & 15;
  const int lg   = lane >> 4;

  const short* Kbase = Kb + (long)b * SEQ * HD;
  const short* Vbase = Vt + (long)b * HD * SEQ;
  const unsigned char* mbase = pmask + (long)b * SEQ;

  const long qrow = (long)b * SEQ + q0 + w * 16 + lc;
  bf16x8 qf[2];
  #pragma unroll
  for (int s = 0; s < 2; ++s)
    qf[s] = *(const bf16x8*)&Qb[qrow * HD + s * 32 + lg * 8];

  f32x4 o[4];
  #pragma unroll
  for (int n = 0; n < 4; ++n)
    #pragma unroll
    for (int i = 0; i < 4; ++i) o[n][i] = 0.f;
  float m[4], l[4];
  #pragma unroll
  for (int r = 0; r < 4; ++r) { m[r] = NEGV; l[r] = 0.f; }

  for (int kt = kt_begin; kt < kt_end; ++kt) {
    // --- QK^T: K fragments straight from global (L2) ---
    bf16x8 kf[4][2];
    #pragma unroll
    for (int n = 0; n < 4; ++n)
      #pragma unroll
      for (int s = 0; s < 2; ++s)
        kf[n][s] = *(const bf16x8*)&Kbase[(long)(kt * 64 + n * 16 + lc) * HD + s * 32 + lg * 8];
    float madd[4];
    #pragma unroll
    for (int n = 0; n < 4; ++n)
      madd[n] = mbase[kt * 64 + n * 16 + lc] ? NEGV : 0.f;

    f32x4 sf[4];
    __builtin_amdgcn_s_setprio(1);
    #pragma unroll
    for (int n = 0; n < 4; ++n) {
      f32x4 acc;
      #pragma unroll
      for (int i = 0; i < 4; ++i) acc[i] = 0.f;
      #pragma unroll
      for (int s = 0; s < 2; ++s)
        acc = __builtin_amdgcn_mfma_f32_16x16x32_bf16(qf[s], kf[n][s], acc, 0, 0, 0);
      sf[n] = acc;
    }
    __builtin_amdgcn_s_setprio(0);

    // --- V fragments: issue early so L2 latency hides under softmax ---
    bf16x8 vf[4][2];
    #pragma unroll
    for (int n = 0; n < 4; ++n)
      #pragma unroll
      for (int s = 0; s < 2; ++s)
        vf[n][s] = *(const bf16x8*)&Vbase[(long)(n * 16 + lc) * SEQ + kt * 64 + s * 32 + lg * 8];

    // --- scale + masks ---
    const bool diag = (kt == qt);
    #pragma unroll
    for (int n = 0; n < 4; ++n) {
      const int key = kt * 64 + n * 16 + lc;
      #pragma unroll
      for (int r = 0; r < 4; ++r) {
        float v = sf[n][r] * 0.125f + madd[n];
        if (diag) {
          const int q = q0 + w * 16 + lg * 4 + r;
          if (key > q) v = NEGV;
        }
        sf[n][r] = v;
      }
    }

    // --- online softmax (keys live in (n, lc); queries in (lg, r)) ---
    float tm[4];
    #pragma unroll
    for (int r = 0; r < 4; ++r)
      tm[r] = fmaxf(fmaxf(sf[0][r], sf[1][r]), fmaxf(sf[2][r], sf[3][r]));
    #pragma unroll
    for (int r = 0; r < 4; ++r) {
      tm[r] = fmaxf(tm[r], __shfl_xor(tm[r], 1));
      tm[r] = fmaxf(tm[r], __shfl_xor(tm[r], 2));
      tm[r] = fmaxf(tm[r], __shfl_xor(tm[r], 4));
      tm[r] = fmaxf(tm[r], __shfl_xor(tm[r], 8));
    }
    float corr[4];
    #pragma unroll
    for (int r = 0; r < 4; ++r) {
      const float mn = fmaxf(m[r], tm[r]);
      corr[r] = __expf(m[r] - mn);
      m[r] = mn;
    }
    float rs[4];
    #pragma unroll
    for (int r = 0; r < 4; ++r) rs[r] = 0.f;
    #pragma unroll
    for (int n = 0; n < 4; ++n)
      #pragma unroll
      for (int r = 0; r < 4; ++r) {
        const float p = __expf(sf[n][r] - m[r]);
        sf[n][r] = p;
        rs[r] += p;
      }
    #pragma unroll
    for (int r = 0; r < 4; ++r) {
      rs[r] += __shfl_xor(rs[r], 1);
      rs[r] += __shfl_xor(rs[r], 2);
      rs[r] += __shfl_xor(rs[r], 4);
      rs[r] += __shfl_xor(rs[r], 8);
      l[r] = l[r] * corr[r] + rs[r];
    }

    // --- P -> per-wave LDS (wave-local, no barrier needed) ---
    #pragma unroll
    for (int n = 0; n < 4; ++n)
      #pragma unroll
      for (int r = 0; r < 4; ++r)
        p_lds[w][(lg * 4 + r) * 72 + n * 16 + lc] = f2bf(sf[n][r]);

    #pragma unroll
    for (int n = 0; n < 4; ++n)
      #pragma unroll
      for (int r = 0; r < 4; ++r)
        o[n][r] *= corr[r];

    bf16x8 pa[2];
    #pragma unroll
    for (int s = 0; s < 2; ++s)
      pa[s] = *(const bf16x8*)&p_lds[w][lc * 72 + s * 32 + lg * 8];

    __builtin_amdgcn_s_setprio(1);
    #pragma unroll
    for (int s = 0; s < 2; ++s)
      #pragma unroll
      for (int n = 0; n < 4; ++n)
        o[n] = __builtin_amdgcn_mfma_f32_16x16x32_bf16(pa[s], vf[n][s], o[n], 0, 0, 0);
    __builtin_amdgcn_s_setprio(0);
  }

  if (SPLIT) {
    #pragma unroll
    for (int r = 0; r < 4; ++r) {
      const long row = (long)b * SEQ + q0 + w * 16 + lg * 4 + r;
      const long prow = (long)quarter * ROWS + row;
      #pragma unroll
      for (int n = 0; n < 4; ++n)
        Opart[prow * HD + n * 16 + lc] = o[n][r];
      if (lc == 0) {
        ml[prow * 2 + 0] = m[r];
        ml[prow * 2 + 1] = l[r];
      }
    }
  } else {
    #pragma unroll
    for (int r = 0; r < 4; ++r) {
      const float inv = 1.f / l[r];
      const long row = (long)b * SEQ + q0 + w * 16 + lg * 4 + r;
      #pragma unroll
      for (int n = 0; n < 4; ++n)
        out[row * HD + n * 16 + lc] = o[n][r] * inv;
    }
  }
}

// ---------------- Kernel 3: merge the four split-K partials -----------------
__global__ __launch_bounds__(256) void combine_kernel(
    const float* __restrict__ Opart, const float* __restrict__ ml,
    float* __restrict__ out)
{
  const int g = blockIdx.x * 256 + threadIdx.x;   // ROWS*16 total
  const int row = g >> 4;
  const int c4  = (g & 15) << 2;
  float mq[4], lq[4];
  #pragma unroll
  for (int q = 0; q < 4; ++q) {
    mq[q] = ml[((long)q * ROWS + row) * 2 + 0];
    lq[q] = ml[((long)q * ROWS + row) * 2 + 1];
  }
  const float M = fmaxf(fmaxf(mq[0], mq[1]), fmaxf(mq[2], mq[3]));
  float wq[4], L = 0.f;
  #pragma unroll
  for (int q = 0; q < 4; ++q) { wq[q] = __expf(mq[q] - M); L += lq[q] * wq[q]; }
  const float inv = 1.f / L;
  f32x4 r;
  #pragma unroll
  for (int j = 0; j < 4; ++j) r[j] = 0.f;
  #pragma unroll
  for (int q = 0; q < 4; ++q) {
    const f32x4 oq = *(const f32x4*)&Opart[((long)q * ROWS + row) * HD + c4];
    #pragma unroll
    for (int j = 0; j < 4; ++j) r[j] += oq[j] * wq[q];
  }
  #pragma unroll
  for (int j = 0; j < 4; ++j) r[j] *= inv;
  *(f32x4*)&out[(long)row * HD + c4] = r;
}

extern "C" void kernel_launch(void* const* d_in, const int* in_sizes, int n_in,
                              void* d_out, int out_size, void* d_ws, size_t ws_size,
                              hipStream_t stream) {
  const float* x  = (const float*)d_in[0];
  const unsigned char* pmask = (const unsigned char*)d_in[1];
  const float* Wq = (const float*)d_in[2];
  const float* bq = (const float*)d_in[3];
  const float* Wk = (const float*)d_in[4];
  const float* bk = (const float*)d_in[5];
  const float* Wv = (const float*)d_in[6];
  const float* bv = (const float*)d_in[7];
  float* out = (float*)d_out;

  short* Qb = (short*)d_ws;                         // [B*T*H] bf16
  short* Kb = Qb + (size_t)ROWS * HD;               // [B*T*H] bf16
  short* Vt = Kb + (size_t)ROWS * HD;               // [B*H*T] bf16
  short* Wt = Vt + (size_t)ROWS * HD;               // [192*512] bf16
  float* Opart = (float*)(Wt + 192 * DIM);          // [4][ROWS][HD] f32
  float* ml    = Opart + 4ull * ROWS * HD;          // [4][ROWS][2] f32

  const size_t need = ((size_t)3 * ROWS * HD + 192 * DIM) * 2 +
                      (4ull * ROWS * HD + 4ull * ROWS * 2) * 4;
  const bool split = ws_size >= need;

  prep_w<<<dim3(24), dim3(256), 0, stream>>>(Wq, Wk, Wv, Wt);
  qkv_gemm<<<dim3(ROWS / 32), dim3(256), 0, stream>>>(
      x, Wt, bq, bk, bv, Qb, Kb, Vt);
  if (split) {
    attn_kernel<true><<<dim3(1024), dim3(256), 0, stream>>>(
        Qb, Kb, Vt, pmask, out, Opart, ml);
    combine_kernel<<<dim3(ROWS * 16 / 256), dim3(256), 0, stream>>>(Opart, ml, out);
  } else {
    attn_kernel<false><<<dim3(256), dim3(256), 0, stream>>>(
        Qb, Kb, Vt, pmask, out, Opart, ml);
  }
}

// Round 5
// 61.871 us; speedup vs baseline: 1.0515x; 1.0515x over previous
//
#include <hip/hip_runtime.h>
#include <hip/hip_bf16.h>

#define BATCH 8
#define SEQ   2048
#define DIM   512
#define HD    64
#define NEGV  (-1e30f)
#define ROWS  (BATCH * SEQ)   // 16384

typedef float f32x4  __attribute__((ext_vector_type(4)));
typedef short bf16x8 __attribute__((ext_vector_type(8)));
typedef short bf16x4 __attribute__((ext_vector_type(4)));

__device__ __forceinline__ short f2bf(float f) {
  unsigned u = __builtin_bit_cast(unsigned, f);
  u += 0x7fffu + ((u >> 16) & 1u);
  return (short)(u >> 16);
}

// ---------------- Kernel 0: W transpose+convert -> Wt bf16 [192][512] -------
__global__ __launch_bounds__(256) void prep_w(
    const float* __restrict__ Wq, const float* __restrict__ Wk,
    const float* __restrict__ Wv, short* __restrict__ Wt)
{
  __shared__ float lds[64][65];
  const int mat = blockIdx.x % 3;
  const int kb  = blockIdx.x / 3;
  const float* W = mat == 0 ? Wq : (mat == 1 ? Wk : Wv);
  const int tid = threadIdx.x;

  #pragma unroll
  for (int i = 0; i < 4; ++i) {
    const int kr = i * 16 + (tid >> 4);
    const int col = (tid & 15) * 4;
    *(float4*)&lds[kr][col] = *(const float4*)&W[(kb * 64 + kr) * HD + col];
  }
  __syncthreads();
  #pragma unroll
  for (int i = 0; i < 2; ++i) {
    const int c = tid + i * 256;
    const int n = c >> 3, seg = c & 7;
    bf16x8 o;
    #pragma unroll
    for (int j = 0; j < 8; ++j) o[j] = f2bf(lds[seg * 8 + j][n]);
    *(bf16x8*)&Wt[(mat * 64 + n) * DIM + kb * 64 + seg * 8] = o;
  }
}

// ---------------- Kernel 1: QKV via MFMA, 512 thr, 64-row tile, BK=64 -------
// 8 waves: wave w -> rows (w>>2)*32..+31, cols (w&3)*48..+47. 8 K-iterations.
__global__ __launch_bounds__(512) void qkv_gemm(
    const float* __restrict__ x, const short* __restrict__ Wt,
    const float* __restrict__ bq, const float* __restrict__ bk,
    const float* __restrict__ bv,
    short* __restrict__ Qb, short* __restrict__ Kb, short* __restrict__ Vt)
{
  __shared__ short xs[64 * 72];   // [row][k0..63], stride 72 (144B)
  __shared__ short ws[192 * 72];  // [col][k0..63]

  const int tid  = threadIdx.x;
  const int lane = tid & 63;
  const int w    = tid >> 6;
  const int wm   = w >> 2;        // 0..1
  const int wn   = w & 3;         // 0..3
  const int lc   = lane & 15;
  const int lg   = lane >> 4;
  const long r0  = (long)blockIdx.x * 64;

  f32x4 acc[2][3];
  #pragma unroll
  for (int m = 0; m < 2; ++m)
    #pragma unroll
    for (int n = 0; n < 3; ++n)
      #pragma unroll
      for (int i = 0; i < 4; ++i) acc[m][n][i] = 0.f;

  float4 xv[2];
  bf16x8 wv[3];

  auto load_tile = [&](int k0) {
    #pragma unroll
    for (int i = 0; i < 2; ++i) {
      const int c = tid + i * 512, row = c >> 4, seg = c & 15;
      xv[i] = *(const float4*)&x[(r0 + row) * DIM + k0 + seg * 4];
    }
    #pragma unroll
    for (int i = 0; i < 3; ++i) {
      const int c = tid + i * 512, row = c >> 3, seg = c & 7;
      wv[i] = *(const bf16x8*)&Wt[row * DIM + k0 + seg * 8];
    }
  };
  auto write_tile = [&]() {
    #pragma unroll
    for (int i = 0; i < 2; ++i) {
      const int c = tid + i * 512, row = c >> 4, seg = c & 15;
      bf16x4 t;
      t[0] = f2bf(xv[i].x); t[1] = f2bf(xv[i].y);
      t[2] = f2bf(xv[i].z); t[3] = f2bf(xv[i].w);
      *(bf16x4*)&xs[row * 72 + seg * 4] = t;
    }
    #pragma unroll
    for (int i = 0; i < 3; ++i) {
      const int c = tid + i * 512, row = c >> 3, seg = c & 7;
      *(bf16x8*)&ws[row * 72 + seg * 8] = wv[i];
    }
  };

  load_tile(0);
  write_tile();
  __syncthreads();

  for (int kt = 0; kt < 8; ++kt) {
    if (kt < 7) load_tile((kt + 1) * 64);

    #pragma unroll
    for (int kk = 0; kk < 2; ++kk) {
      bf16x8 a[2], b[3];
      #pragma unroll
      for (int m = 0; m < 2; ++m)
        a[m] = *(const bf16x8*)&xs[(wm * 32 + m * 16 + lc) * 72 + kk * 32 + lg * 8];
      #pragma unroll
      for (int n = 0; n < 3; ++n)
        b[n] = *(const bf16x8*)&ws[(wn * 48 + n * 16 + lc) * 72 + kk * 32 + lg * 8];
      __builtin_amdgcn_s_setprio(1);
      #pragma unroll
      for (int m = 0; m < 2; ++m)
        #pragma unroll
        for (int n = 0; n < 3; ++n)
          acc[m][n] = __builtin_amdgcn_mfma_f32_16x16x32_bf16(a[m], b[n], acc[m][n], 0, 0, 0);
      __builtin_amdgcn_s_setprio(0);
    }

    __syncthreads();
    if (kt < 7) {
      write_tile();
      __syncthreads();
    }
  }

  #pragma unroll
  for (int n = 0; n < 3; ++n) {
    const int col = wn * 48 + n * 16 + lc;
    const int mat = col >> 6;            // wave-uniform per n
    const int h   = col & 63;
    const float bias = (mat == 0 ? bq : (mat == 1 ? bk : bv))[h];
    #pragma unroll
    for (int m = 0; m < 2; ++m)
      #pragma unroll
      for (int r = 0; r < 4; ++r) {
        const long row = r0 + wm * 32 + m * 16 + lg * 4 + r;
        const short o = f2bf(acc[m][n][r] + bias);
        if (mat == 0)      Qb[row * HD + h] = o;
        else if (mat == 1) Kb[row * HD + h] = o;
        else {
          const int bb = (int)(row >> 11), t = (int)(row & 2047);
          Vt[((long)bb * HD + h) * SEQ + t] = o;
        }
      }
  }
}

// ---------------- Kernel 2: flash attention, swapped QK^T, 4-way split-K ----
// mfma(K,Q) -> S[key][query]: query = lane&15 (one per lane!), key = lg*4+r+16n.
// Softmax is in-lane (15-op trees) + 2 shfl_xor. P repacked via per-wave LDS.
template<bool SPLIT>
__global__ __launch_bounds__(256) void attn_kernel(
    const short* __restrict__ Qb, const short* __restrict__ Kb,
    const short* __restrict__ Vt, const unsigned char* __restrict__ pmask,
    float* __restrict__ out, float* __restrict__ Opart, float* __restrict__ ml)
{
  __shared__ short p_lds[4][16 * 72];

  const int bid = blockIdx.x;
  int b, qt, quarter;
  if (SPLIT) {
    quarter = bid >> 8;
    const int t = bid & 255;
    b = t >> 5;
    const int v = t & 31;
    qt = (quarter & 1) ? 31 - v : v;
  } else {
    b = bid >> 5; qt = bid & 31; quarter = 0;
  }

  const int nkt      = qt + 1;
  const int kt_begin = SPLIT ? (nkt * quarter) >> 2 : 0;
  const int kt_end   = SPLIT ? (nkt * (quarter + 1)) >> 2 : nkt;
  const int q0       = qt * 64;
  const int tid      = threadIdx.x;

  if (SPLIT && kt_begin >= kt_end) {
    #pragma unroll
    for (int i = 0; i < 4; ++i) {
      const int idx = tid + i * 256;
      const int rr = idx >> 4;
      const long row = (long)b * SEQ + q0 + rr;
      f32x4 z; z[0] = 0.f; z[1] = 0.f; z[2] = 0.f; z[3] = 0.f;
      *(f32x4*)&Opart[((long)quarter * ROWS + row) * HD + (idx & 15) * 4] = z;
    }
    if (tid < 64) {
      const long row = (long)b * SEQ + q0 + tid;
      ml[((long)quarter * ROWS + row) * 2 + 0] = NEGV;
      ml[((long)quarter * ROWS + row) * 2 + 1] = 0.f;
    }
    return;
  }

  const int w    = tid >> 6;
  const int lane = tid & 63;
  const int lc   = lane & 15;
  const int lg   = lane >> 4;

  const short* Kbase = Kb + (long)b * SEQ * HD;
  const short* Vbase = Vt + (long)b * HD * SEQ;
  const unsigned char* mbase = pmask + (long)b * SEQ;

  const long qrow = (long)b * SEQ + q0 + w * 16 + lc;
  bf16x8 qf[2];
  #pragma unroll
  for (int s = 0; s < 2; ++s)
    qf[s] = *(const bf16x8*)&Qb[qrow * HD + s * 32 + lg * 8];

  f32x4 o[4];
  #pragma unroll
  for (int n = 0; n < 4; ++n)
    #pragma unroll
    for (int i = 0; i < 4; ++i) o[n][i] = 0.f;
  float m = NEGV, l = 0.f;          // per-lane: stats for query q0+w*16+lc
  const int q = q0 + w * 16 + lc;

  for (int kt = kt_begin; kt < kt_end; ++kt) {
    // --- K fragments + padding-mask words (global/L2) ---
    bf16x8 kf[4][2];
    #pragma unroll
    for (int n = 0; n < 4; ++n)
      #pragma unroll
      for (int s = 0; s < 2; ++s)
        kf[n][s] = *(const bf16x8*)&Kbase[(long)(kt * 64 + n * 16 + lc) * HD + s * 32 + lg * 8];
    unsigned mw[4];
    #pragma unroll
    for (int n = 0; n < 4; ++n)
      mw[n] = *(const unsigned*)&mbase[kt * 64 + n * 16 + lg * 4];

    // --- S^T = K Q^T : D[key][query], query = lc ---
    f32x4 sf[4];
    __builtin_amdgcn_s_setprio(1);
    #pragma unroll
    for (int n = 0; n < 4; ++n) {
      f32x4 acc;
      #pragma unroll
      for (int i = 0; i < 4; ++i) acc[i] = 0.f;
      #pragma unroll
      for (int s = 0; s < 2; ++s)
        acc = __builtin_amdgcn_mfma_f32_16x16x32_bf16(kf[n][s], qf[s], acc, 0, 0, 0);
      sf[n] = acc;
    }
    __builtin_amdgcn_s_setprio(0);

    // --- V fragments: issue now (kf regs dead -> reuse), consumed after softmax
    bf16x8 vf[4][2];
    #pragma unroll
    for (int n = 0; n < 4; ++n)
      #pragma unroll
      for (int s = 0; s < 2; ++s)
        vf[n][s] = *(const bf16x8*)&Vbase[(long)(n * 16 + lc) * SEQ + kt * 64 + s * 32 + lg * 8];

    // --- scale + masks (key = kt*64 + n*16 + lg*4 + r) ---
    const bool diag = (kt == qt);
    #pragma unroll
    for (int n = 0; n < 4; ++n)
      #pragma unroll
      for (int r = 0; r < 4; ++r) {
        const int key = kt * 64 + n * 16 + lg * 4 + r;
        float v = sf[n][r] * 0.125f;
        if ((mw[n] >> (8 * r)) & 0xff) v = NEGV;
        if (diag && key > q) v = NEGV;
        sf[n][r] = v;
      }

    // --- lane-local softmax: in-lane tree + 2 shfl_xor ---
    float t4[4];
    #pragma unroll
    for (int n = 0; n < 4; ++n)
      t4[n] = fmaxf(fmaxf(sf[n][0], sf[n][1]), fmaxf(sf[n][2], sf[n][3]));
    float tm = fmaxf(fmaxf(t4[0], t4[1]), fmaxf(t4[2], t4[3]));
    tm = fmaxf(tm, __shfl_xor(tm, 16));
    tm = fmaxf(tm, __shfl_xor(tm, 32));
    const float mn = fmaxf(m, tm);
    const float corr = __expf(m - mn);
    m = mn;
    float rs4[4];
    #pragma unroll
    for (int n = 0; n < 4; ++n) {
      rs4[n] = 0.f;
      #pragma unroll
      for (int r = 0; r < 4; ++r) {
        const float p = __expf(sf[n][r] - m);
        sf[n][r] = p;
        rs4[n] += p;
      }
    }
    float rs = (rs4[0] + rs4[1]) + (rs4[2] + rs4[3]);
    rs += __shfl_xor(rs, 16);
    rs += __shfl_xor(rs, 32);
    l = l * corr + rs;

    // --- P -> per-wave LDS: row = query (lc), 4 consecutive keys per write ---
    #pragma unroll
    for (int n = 0; n < 4; ++n) {
      bf16x4 t;
      #pragma unroll
      for (int r = 0; r < 4; ++r) t[r] = f2bf(sf[n][r]);
      *(bf16x4*)&p_lds[w][lc * 72 + n * 16 + lg * 4] = t;
    }

    // --- corr broadcast to O layout (query = lg*4+r) + rescale ---
    float cb[4];
    #pragma unroll
    for (int r = 0; r < 4; ++r) cb[r] = __shfl(corr, lg * 4 + r);
    #pragma unroll
    for (int n = 0; n < 4; ++n)
      #pragma unroll
      for (int r = 0; r < 4; ++r)
        o[n][r] *= cb[r];

    bf16x8 pa[2];
    #pragma unroll
    for (int s = 0; s < 2; ++s)
      pa[s] = *(const bf16x8*)&p_lds[w][lc * 72 + s * 32 + lg * 8];

    __builtin_amdgcn_s_setprio(1);
    #pragma unroll
    for (int s = 0; s < 2; ++s)
      #pragma unroll
      for (int n = 0; n < 4; ++n)
        o[n] = __builtin_amdgcn_mfma_f32_16x16x32_bf16(pa[s], vf[n][s], o[n], 0, 0, 0);
    __builtin_amdgcn_s_setprio(0);
  }

  if (SPLIT) {
    #pragma unroll
    for (int r = 0; r < 4; ++r) {
      const long row = (long)b * SEQ + q0 + w * 16 + lg * 4 + r;
      const long prow = (long)quarter * ROWS + row;
      #pragma unroll
      for (int n = 0; n < 4; ++n)
        Opart[prow * HD + n * 16 + lc] = o[n][r];
    }
    if (lg == 0) {    // stats live at lane lc = query
      const long prow = (long)quarter * ROWS + (long)b * SEQ + q0 + w * 16 + lc;
      ml[prow * 2 + 0] = m;
      ml[prow * 2 + 1] = l;
    }
  } else {
    #pragma unroll
    for (int r = 0; r < 4; ++r) {
      const float lq = __shfl(l, lg * 4 + r);
      const float inv = 1.f / lq;
      const long row = (long)b * SEQ + q0 + w * 16 + lg * 4 + r;
      #pragma unroll
      for (int n = 0; n < 4; ++n)
        out[row * HD + n * 16 + lc] = o[n][r] * inv;
    }
  }
}

// ---------------- Kernel 3: merge the four split-K partials -----------------
__global__ __launch_bounds__(256) void combine_kernel(
    const float* __restrict__ Opart, const float* __restrict__ ml,
    float* __restrict__ out)
{
  const int g = blockIdx.x * 256 + threadIdx.x;   // ROWS*16 total
  const int row = g >> 4;
  const int c4  = (g & 15) << 2;
  float mq[4], lq[4];
  #pragma unroll
  for (int q = 0; q < 4; ++q) {
    mq[q] = ml[((long)q * ROWS + row) * 2 + 0];
    lq[q] = ml[((long)q * ROWS + row) * 2 + 1];
  }
  const float M = fmaxf(fmaxf(mq[0], mq[1]), fmaxf(mq[2], mq[3]));
  float wq[4], L = 0.f;
  #pragma unroll
  for (int q = 0; q < 4; ++q) { wq[q] = __expf(mq[q] - M); L += lq[q] * wq[q]; }
  const float inv = 1.f / L;
  f32x4 r;
  #pragma unroll
  for (int j = 0; j < 4; ++j) r[j] = 0.f;
  #pragma unroll
  for (int q = 0; q < 4; ++q) {
    const f32x4 oq = *(const f32x4*)&Opart[((long)q * ROWS + row) * HD + c4];
    #pragma unroll
    for (int j = 0; j < 4; ++j) r[j] += oq[j] * wq[q];
  }
  #pragma unroll
  for (int j = 0; j < 4; ++j) r[j] *= inv;
  *(f32x4*)&out[(long)row * HD + c4] = r;
}

extern "C" void kernel_launch(void* const* d_in, const int* in_sizes, int n_in,
                              void* d_out, int out_size, void* d_ws, size_t ws_size,
                              hipStream_t stream) {
  const float* x  = (const float*)d_in[0];
  const unsigned char* pmask = (const unsigned char*)d_in[1];
  const float* Wq = (const float*)d_in[2];
  const float* bq = (const float*)d_in[3];
  const float* Wk = (const float*)d_in[4];
  const float* bk = (const float*)d_in[5];
  const float* Wv = (const float*)d_in[6];
  const float* bv = (const float*)d_in[7];
  float* out = (float*)d_out;

  short* Qb = (short*)d_ws;                         // [B*T*H] bf16
  short* Kb = Qb + (size_t)ROWS * HD;               // [B*T*H] bf16
  short* Vt = Kb + (size_t)ROWS * HD;               // [B*H*T] bf16
  short* Wt = Vt + (size_t)ROWS * HD;               // [192*512] bf16
  float* Opart = (float*)(Wt + 192 * DIM);          // [4][ROWS][HD] f32
  float* ml    = Opart + 4ull * ROWS * HD;          // [4][ROWS][2] f32

  const size_t need = ((size_t)3 * ROWS * HD + 192 * DIM) * 2 +
                      (4ull * ROWS * HD + 4ull * ROWS * 2) * 4;
  const bool split = ws_size >= need;

  prep_w<<<dim3(24), dim3(256), 0, stream>>>(Wq, Wk, Wv, Wt);
  qkv_gemm<<<dim3(ROWS / 64), dim3(512), 0, stream>>>(
      x, Wt, bq, bk, bv, Qb, Kb, Vt);
  if (split) {
    attn_kernel<true><<<dim3(1024), dim3(256), 0, stream>>>(
        Qb, Kb, Vt, pmask, out, Opart, ml);
    combine_kernel<<<dim3(ROWS * 16 / 256), dim3(256), 0, stream>>>(Opart, ml, out);
  } else {
    attn_kernel<false><<<dim3(256), dim3(256), 0, stream>>>(
        Qb, Kb, Vt, pmask, out, Opart, ml);
  }
}